// Round 7
// baseline (336.231 us; speedup 1.0000x reference)
//
#include <hip/hip_runtime.h>

// Multiresolution hash encoding, MI355X. Round 7: padded-bin bucketing.
// R6 lesson: Morton sorting cuts main kernel 171->133us, but counting-sort
// preprocessing (hist+scan+scatter, 4 dispatches) cost ~47us. Replace with
// single-pass scatter into capacity-128 padded bins (4096 bins, Poisson(64)
// occupancy; overflow prob ~1e-13/bin, guarded by inline direct compute).
// Main kernel: R5 pair-load body + per-lane-masked B-loads (only odd-c0 lanes
// need the second line of an x-corner pair) + chunked XCD swizzle.

constexpr int      kT      = 524288;     // 2^19 rows per level
constexpr unsigned kMask   = kT - 1;
constexpr int      kB      = 262144;
constexpr unsigned kP1     = 2654435761u;
constexpr unsigned kP2     = 805459861u;
constexpr int      kBins   = 4096;
constexpr int      kCap    = 128;        // slots per bin (2 waves)

typedef float f32x4 __attribute__((ext_vector_type(4)));

__device__ __forceinline__ unsigned morton12(float x0, float x1, float x2) {
    unsigned a = min(15u, (unsigned)(x0 * 16.0f));
    unsigned b = min(15u, (unsigned)(x1 * 16.0f));
    unsigned c = min(15u, (unsigned)(x2 * 16.0f));
    unsigned key = 0;
#pragma unroll
    for (int i = 3; i >= 0; --i)
        key = (key << 3) | (((a >> i) & 1u) << 2) | (((b >> i) & 1u) << 1) | ((c >> i) & 1u);
    return key;
}

// ---- main compute body: pair-load (dim0 prime==1) + masked B-loads ----
__device__ __forceinline__ void hashenc_body(const float x0, const float x1, const float x2,
                                             const f32x4* __restrict__ tab4base,
                                             f32x4* __restrict__ out, const unsigned sid) {
    f32x4 o[8];
    // floor(16 * b^l), b = 2^(1/3): rounding-traced, verified (absmax 4.8e-7)
    constexpr float kResF[16] = {16, 20, 25, 32, 40, 50, 64, 80,
                                 101, 128, 161, 203, 256, 322, 406, 512};
#pragma unroll
    for (int l = 0; l < 16; ++l) {
        const float res = kResF[l];
        const float s0 = x0 * res, s1 = x1 * res, s2 = x2 * res;
        const float f0 = floorf(s0), f1 = floorf(s1), f2 = floorf(s2);
        const float r0 = s0 - f0, r1 = s1 - f1, r2 = s2 - f2;
        const unsigned c0 = (unsigned)f0;
        const unsigned h1a = (unsigned)f1 * kP1, h1b = h1a + kP1;
        const unsigned h2a = (unsigned)f2 * kP2, h2b = h2a + kP2;
        const float w0a = 1.0f - r0, w1a = 1.0f - r1, w2a = 1.0f - r2;
        const f32x4* __restrict__ tab4 = tab4base + (size_t)l * (kT / 2);

        unsigned i0[4], i1[4];
#pragma unroll
        for (int q = 0; q < 4; ++q) {
            const unsigned g = ((q & 1) ? h1b : h1a) ^ ((q & 2) ? h2b : h2a);
            i0[q] = (c0 ^ g) & kMask;
            i1[q] = ((c0 + 1u) ^ g) & kMask;
        }
        f32x4 A[4], Bv[4];
#pragma unroll
        for (int q = 0; q < 4; ++q) A[q] = tab4[i0[q] >> 1];
        const bool odd = (c0 & 1u) != 0u;
        if (odd) {  // exec-masked: only odd-c0 lanes generate addresses
#pragma unroll
            for (int q = 0; q < 4; ++q) Bv[q] = tab4[i1[q] >> 1];
        }
        float a0 = 0.0f, a1 = 0.0f;
#pragma unroll
        for (int q = 0; q < 4; ++q) {
            const float p0x = (i0[q] & 1) ? A[q].z : A[q].x;
            const float p0y = (i0[q] & 1) ? A[q].w : A[q].y;
            // even c0: second corner is the other half of A; odd: from Bv
            const float e1x = (i0[q] & 1) ? A[q].x : A[q].z;
            const float e1y = (i0[q] & 1) ? A[q].y : A[q].w;
            const float b1x = (i1[q] & 1) ? Bv[q].z : Bv[q].x;
            const float b1y = (i1[q] & 1) ? Bv[q].w : Bv[q].y;
            const float p1x = odd ? b1x : e1x;
            const float p1y = odd ? b1y : e1y;
            const float wyz = ((q & 1) ? r1 : w1a) * ((q & 2) ? r2 : w2a);
            const float wl = wyz * w0a;
            const float wr = wyz * r0;
            a0 = fmaf(wl, p0x, fmaf(wr, p1x, a0));
            a1 = fmaf(wl, p0y, fmaf(wr, p1y, a1));
        }
        if (l & 1) { o[l >> 1].z = a0; o[l >> 1].w = a1; }
        else       { o[l >> 1].x = a0; o[l >> 1].y = a1; }
    }
    f32x4* op = out + (size_t)sid * 8;
#pragma unroll
    for (int k = 0; k < 8; ++k) __builtin_nontemporal_store(o[k], op + k);
}

__global__ __launch_bounds__(256) void scatter_kernel(const float* __restrict__ x,
                                                      unsigned* __restrict__ cnt,
                                                      f32x4* __restrict__ xsort,
                                                      const f32x4* __restrict__ tab4,
                                                      f32x4* __restrict__ out) {
    const int i = blockIdx.x * 256 + threadIdx.x;
    const float x0 = x[3 * i], x1 = x[3 * i + 1], x2 = x[3 * i + 2];
    const unsigned key = morton12(x0, x1, x2);
    const unsigned slot = atomicAdd(&cnt[key], 1u);
    if (slot < (unsigned)kCap) {
        f32x4 v;
        v.x = x0; v.y = x1; v.z = x2; v.w = __uint_as_float((unsigned)i);
        xsort[key * kCap + slot] = v;
    } else {
        // ~1e-13 probability safety net: compute this sample directly
        hashenc_body(x0, x1, x2, tab4, out, (unsigned)i);
    }
}

__global__ __launch_bounds__(256) void hashenc_sorted(const f32x4* __restrict__ xsort,
                                                      const unsigned* __restrict__ cnt,
                                                      const f32x4* __restrict__ tab4base,
                                                      f32x4* __restrict__ out) {
    // chunked XCD swizzle: XCD k owns contiguous Morton chunk k (2048 = 8*256)
    const int bid = (int)((blockIdx.x & 7) * 256 + (blockIdx.x >> 3));
    const int gs  = bid * 256 + threadIdx.x;
    const int bin = gs >> 7;          // kCap = 128
    const int sl  = gs & (kCap - 1);
    const unsigned n = min(cnt[bin], (unsigned)kCap);
    if ((unsigned)sl >= n) return;    // empty padded slots: wave exits/masks
    const f32x4 v = xsort[gs];
    hashenc_body(v.x, v.y, v.z, tab4base, out, __float_as_uint(v.w));
}

__global__ __launch_bounds__(256) void hashenc_direct(const float* __restrict__ x,
                                                      const f32x4* __restrict__ tab4base,
                                                      f32x4* __restrict__ out) {
    const int i = blockIdx.x * 256 + threadIdx.x;
    hashenc_body(x[3 * i], x[3 * i + 1], x[3 * i + 2], tab4base, out, (unsigned)i);
}

extern "C" void kernel_launch(void* const* d_in, const int* in_sizes, int n_in,
                              void* d_out, int out_size, void* d_ws, size_t ws_size,
                              hipStream_t stream) {
    const float*  x    = (const float*)d_in[0];
    const f32x4*  tab4 = (const f32x4*)d_in[1];
    f32x4*        out  = (f32x4*)d_out;

    const size_t cntBytes   = (size_t)kBins * 4;
    const size_t xsortBytes = (size_t)kBins * kCap * 16;  // 8 MB
    const size_t need = cntBytes + xsortBytes;

    if (ws_size >= need) {
        unsigned* cnt   = (unsigned*)d_ws;
        f32x4*    xsort = (f32x4*)((char*)d_ws + cntBytes);
        hipMemsetAsync(cnt, 0, cntBytes, stream);
        scatter_kernel<<<kB / 256, 256, 0, stream>>>(x, cnt, xsort, tab4, out);
        hashenc_sorted<<<(kBins * kCap) / 256, 256, 0, stream>>>(xsort, cnt, tab4, out);
    } else {
        hashenc_direct<<<kB / 256, 256, 0, stream>>>(x, tab4, out);
    }
}

// Round 8
// 166.324 us; speedup vs baseline: 2.0215x; 2.0215x over previous
//
#include <hip/hip_runtime.h>

// Multiresolution hash encoding, MI355X. Round 8.
// R7 post-mortem: masked-B-loads -> 256 VGPR / 8% occupancy (revert to R6 body,
// 48 VGPR); nontemporal scattered stores -> 3.5x write amplification (revert to
// plain stores). Keep R6's Morton bucketing but replace the 4-dispatch counting
// sort with a single-pass padded-bin scatter (cap 128, Poisson(64) occupancy;
// overflow list + block-0 cleanup guarantees correctness). Main kernel at
// launch_bounds(256,8): padding idles ~half the waves, so double co-residency.

constexpr int      kT      = 524288;     // 2^19 rows per level
constexpr unsigned kMask   = kT - 1;
constexpr int      kB      = 262144;
constexpr unsigned kP1     = 2654435761u;
constexpr unsigned kP2     = 805459861u;
constexpr int      kBins   = 4096;
constexpr int      kCap    = 128;        // slots per bin (2 waves)
constexpr int      kOvfCap = 65536;      // overflow list capacity (never filled)

typedef float f32x4 __attribute__((ext_vector_type(4)));

__device__ __forceinline__ unsigned morton12(float x0, float x1, float x2) {
    unsigned a = min(15u, (unsigned)(x0 * 16.0f));
    unsigned b = min(15u, (unsigned)(x1 * 16.0f));
    unsigned c = min(15u, (unsigned)(x2 * 16.0f));
    unsigned key = 0;
#pragma unroll
    for (int i = 3; i >= 0; --i)
        key = (key << 3) | (((a >> i) & 1u) << 2) | (((b >> i) & 1u) << 1) | ((c >> i) & 1u);
    return key;
}

// ---- main compute body: R5/R6 pair-load structure (dim0 prime==1) ----
__device__ __forceinline__ void hashenc_body(const float x0, const float x1, const float x2,
                                             const f32x4* __restrict__ tab4base,
                                             f32x4* __restrict__ out, const unsigned sid) {
    f32x4 o[8];
    // floor(16 * b^l), b = 2^(1/3): rounding-traced, verified (absmax 4.8e-7)
    constexpr float kResF[16] = {16, 20, 25, 32, 40, 50, 64, 80,
                                 101, 128, 161, 203, 256, 322, 406, 512};
#pragma unroll
    for (int l = 0; l < 16; ++l) {
        const float res = kResF[l];
        const float s0 = x0 * res, s1 = x1 * res, s2 = x2 * res;
        const float f0 = floorf(s0), f1 = floorf(s1), f2 = floorf(s2);
        const float r0 = s0 - f0, r1 = s1 - f1, r2 = s2 - f2;
        const unsigned c0 = (unsigned)f0;
        const unsigned h1a = (unsigned)f1 * kP1, h1b = h1a + kP1;
        const unsigned h2a = (unsigned)f2 * kP2, h2b = h2a + kP2;
        const float w0a = 1.0f - r0, w1a = 1.0f - r1, w2a = 1.0f - r2;
        const f32x4* __restrict__ tab4 = tab4base + (size_t)l * (kT / 2);
        float a0 = 0.0f, a1 = 0.0f;
#pragma unroll
        for (int q = 0; q < 4; ++q) {  // (y,z) corner combos
            const unsigned g = ((q & 1) ? h1b : h1a) ^ ((q & 2) ? h2b : h2a);
            const unsigned i0 = (c0 ^ g) & kMask;
            const unsigned i1 = ((c0 + 1u) ^ g) & kMask;
            const f32x4 A = tab4[i0 >> 1];
            const f32x4 B = tab4[i1 >> 1];  // same line as A when c0 even
            const float p0x = (i0 & 1) ? A.z : A.x;
            const float p0y = (i0 & 1) ? A.w : A.y;
            const float p1x = (i1 & 1) ? B.z : B.x;
            const float p1y = (i1 & 1) ? B.w : B.y;
            const float wyz = ((q & 1) ? r1 : w1a) * ((q & 2) ? r2 : w2a);
            const float wl = wyz * w0a;
            const float wr = wyz * r0;
            a0 = fmaf(wl, p0x, fmaf(wr, p1x, a0));
            a1 = fmaf(wl, p0y, fmaf(wr, p1y, a1));
        }
        if (l & 1) { o[l >> 1].z = a0; o[l >> 1].w = a1; }
        else       { o[l >> 1].x = a0; o[l >> 1].y = a1; }
    }
    f32x4* op = out + (size_t)sid * 8;
#pragma unroll
    for (int k = 0; k < 8; ++k) op[k] = o[k];  // plain stores: full-line assembly in L2
}

// Non-inlined wrapper: keeps scatter_kernel's register footprint small on the
// (probability ~1e-13) overflow fallback path.
__device__ __noinline__ void hashenc_one(const f32x4 v, const f32x4* __restrict__ tab4,
                                         f32x4* __restrict__ out) {
    hashenc_body(v.x, v.y, v.z, tab4, out, __float_as_uint(v.w));
}

__global__ __launch_bounds__(256) void scatter_kernel(const float* __restrict__ x,
                                                      unsigned* __restrict__ cnt,
                                                      f32x4* __restrict__ xsort,
                                                      f32x4* __restrict__ ovf,
                                                      const f32x4* __restrict__ tab4,
                                                      f32x4* __restrict__ out) {
    const int i = blockIdx.x * 256 + threadIdx.x;
    const float x0 = x[3 * i], x1 = x[3 * i + 1], x2 = x[3 * i + 2];
    const unsigned key = morton12(x0, x1, x2);
    const unsigned slot = atomicAdd(&cnt[key], 1u);
    f32x4 v;
    v.x = x0; v.y = x1; v.z = x2; v.w = __uint_as_float((unsigned)i);
    if (slot < (unsigned)kCap) {
        xsort[key * kCap + slot] = v;
    } else {
        const unsigned o = atomicAdd(&cnt[kBins], 1u);
        if (o < (unsigned)kOvfCap) ovf[o] = v;
        else hashenc_one(v, tab4, out);  // unreachable in practice; correctness net
    }
}

__global__ __launch_bounds__(256, 8) void hashenc_sorted(const f32x4* __restrict__ xsort,
                                                         const unsigned* __restrict__ cnt,
                                                         const f32x4* __restrict__ ovf,
                                                         const f32x4* __restrict__ tab4base,
                                                         f32x4* __restrict__ out) {
    if (blockIdx.x == 0) {  // overflow cleanup (count ~always 0)
        const unsigned oc = min(cnt[kBins], (unsigned)kOvfCap);
        for (unsigned j = threadIdx.x; j < oc; j += 256)
            hashenc_one(ovf[j], tab4base, out);
    }
    // chunked XCD swizzle: XCD k owns contiguous Morton chunk (2048 = 8*256)
    const int bid = (int)((blockIdx.x & 7) * 256 + (blockIdx.x >> 3));
    const int gs  = bid * 256 + (int)threadIdx.x;
    const int bin = gs >> 7;          // kCap = 128
    const int sl  = gs & (kCap - 1);
    const unsigned n = min(cnt[bin], (unsigned)kCap);
    if ((unsigned)sl >= n) return;    // padded slots: wave exits/masks quickly
    const f32x4 v = xsort[gs];
    hashenc_body(v.x, v.y, v.z, tab4base, out, __float_as_uint(v.w));
}

__global__ __launch_bounds__(256, 4) void hashenc_direct(const float* __restrict__ x,
                                                         const f32x4* __restrict__ tab4base,
                                                         f32x4* __restrict__ out) {
    const int i = blockIdx.x * 256 + threadIdx.x;
    hashenc_body(x[3 * i], x[3 * i + 1], x[3 * i + 2], tab4base, out, (unsigned)i);
}

extern "C" void kernel_launch(void* const* d_in, const int* in_sizes, int n_in,
                              void* d_out, int out_size, void* d_ws, size_t ws_size,
                              hipStream_t stream) {
    const float*  x    = (const float*)d_in[0];
    const f32x4*  tab4 = (const f32x4*)d_in[1];
    f32x4*        out  = (f32x4*)d_out;

    const size_t cntBytes   = (size_t)(kBins + 16) * 4;       // counters + ovf count
    const size_t ovfBytes   = (size_t)kOvfCap * 16;           // 1 MB
    const size_t xsortBytes = (size_t)kBins * kCap * 16;      // 8 MB
    const size_t need = cntBytes + ovfBytes + xsortBytes;

    if (ws_size >= need) {
        unsigned* cnt   = (unsigned*)d_ws;
        f32x4*    ovf   = (f32x4*)((char*)d_ws + cntBytes);
        f32x4*    xsort = ovf + kOvfCap;
        hipMemsetAsync(cnt, 0, cntBytes, stream);
        scatter_kernel<<<kB / 256, 256, 0, stream>>>(x, cnt, xsort, ovf, tab4, out);
        hashenc_sorted<<<(kBins * kCap) / 256, 256, 0, stream>>>(xsort, cnt, ovf, tab4, out);
    } else {
        hashenc_direct<<<kB / 256, 256, 0, stream>>>(x, tab4, out);
    }
}